// Round 1
// baseline (564.391 us; speedup 1.0000x reference)
//
#include <hip/hip_runtime.h>
#include <hip/hip_bf16.h>

// Problem: B=2048, T=32, V=1024, D=256
//   embed[b][t][d] = codebook[t][argmin_v d2(t,b,v)][d]
//   idx[b][t]      = argmin_v d2(t,b,v),  d2 = |x|^2 - 2 x.c + |c|^2
// argmin only needs score = c2[v] - 2*dot(x,c). fp32 exact (no MFMA this round:
// bf16 rounding flips ~0.7% of argmins -> fails thresholds).

#define B_ 2048
#define T_ 32
#define V_ 1024
#define D_ 256

#define BT 128   // b-rows per block
#define VT 128   // v-cols per tile
#define KC 64    // k-chunk
#define XPAD 4   // pad rows to keep float4 alignment (stride 132 dwords)

// ---------------- prep: c2[t*V+v] = sum_d codebook^2 ----------------
__global__ void c2_kernel(const float* __restrict__ cb, float* __restrict__ c2) {
    int row  = blockIdx.x * 4 + (threadIdx.x >> 6);   // 4 waves/block, 1 row/wave
    int lane = threadIdx.x & 63;
    const float4 v = ((const float4*)(cb + (size_t)row * D_))[lane]; // 64*4 = 256 = D
    float s = v.x*v.x + v.y*v.y + v.z*v.z + v.w*v.w;
    #pragma unroll
    for (int off = 32; off > 0; off >>= 1) s += __shfl_down(s, off, 64);
    if (lane == 0) c2[row] = s;
}

// ---------------- main: fused GEMM + argmin + gather ----------------
__global__ __launch_bounds__(256, 2)
void vq_kernel(const float* __restrict__ x, const float* __restrict__ cb,
               const float* __restrict__ c2, float* __restrict__ out) {
    const int t  = blockIdx.x;        // 0..31
    const int b0 = blockIdx.y * BT;   // row base

    __shared__ float Xs[KC][BT + XPAD];  // transposed: [k][row]
    __shared__ float Cs[KC][VT + XPAD];  // transposed: [k][v]
    __shared__ int   Idx[BT];

    const int tid = threadIdx.x;
    const int tx  = tid & 15;         // v-group
    const int ty  = tid >> 4;         // row-group

    float m[8];
    int   mi[8];
    #pragma unroll
    for (int r = 0; r < 8; ++r) { m[r] = 3.4e38f; mi[r] = 0; }

    const int kq    = tid & 15;       // float4 column for staging
    const int rbase = tid >> 4;       // staging row base (16 rows, step 16)

    for (int vt = 0; vt < V_ / VT; ++vt) {
        float acc[8][8];
        #pragma unroll
        for (int r = 0; r < 8; ++r)
            #pragma unroll
            for (int v = 0; v < 8; ++v) acc[r][v] = 0.0f;

        for (int kc = 0; kc < D_ / KC; ++kc) {
            __syncthreads();  // previous tile's readers done
            // stage X tile (coalesced along d, transposed into LDS)
            #pragma unroll
            for (int i = 0; i < 8; ++i) {
                int row = rbase + i * 16;
                const float4 vv = *(const float4*)(x + (((size_t)(b0 + row)) * T_ + t) * D_ + kc * KC + kq * 4);
                Xs[kq*4+0][row] = vv.x; Xs[kq*4+1][row] = vv.y;
                Xs[kq*4+2][row] = vv.z; Xs[kq*4+3][row] = vv.w;
            }
            // stage C tile
            #pragma unroll
            for (int i = 0; i < 8; ++i) {
                int row = rbase + i * 16;
                const float4 vv = *(const float4*)(cb + ((size_t)t * V_ + vt * VT + row) * D_ + kc * KC + kq * 4);
                Cs[kq*4+0][row] = vv.x; Cs[kq*4+1][row] = vv.y;
                Cs[kq*4+2][row] = vv.z; Cs[kq*4+3][row] = vv.w;
            }
            __syncthreads();

            #pragma unroll 4
            for (int k = 0; k < KC; ++k) {
                float xf[8], cf[8];
                *(float4*)&xf[0] = *(const float4*)&Xs[k][ty * 8];
                *(float4*)&xf[4] = *(const float4*)&Xs[k][ty * 8 + 4];
                *(float4*)&cf[0] = *(const float4*)&Cs[k][tx * 8];
                *(float4*)&cf[4] = *(const float4*)&Cs[k][tx * 8 + 4];
                #pragma unroll
                for (int r = 0; r < 8; ++r)
                    #pragma unroll
                    for (int v = 0; v < 8; ++v)
                        acc[r][v] = fmaf(xf[r], cf[v], acc[r][v]);
            }
        }

        // epilogue for this v-tile: running argmin (v strictly increases over
        // vt and j, so strict < keeps the earliest index like np.argmin)
        #pragma unroll
        for (int j = 0; j < 8; ++j) {
            const int v = vt * VT + tx * 8 + j;
            const float cc = c2[t * V_ + v];
            #pragma unroll
            for (int r = 0; r < 8; ++r) {
                const float s = fmaf(-2.0f, acc[r][j], cc);
                if (s < m[r]) { m[r] = s; mi[r] = v; }
            }
        }
    }

    // cross-thread argmin reduce over the 16 v-groups (reuse staging LDS)
    __syncthreads();
    float* Ms = (float*)Xs;   // [BT][16]
    int*   Is = (int*)Cs;     // [BT][16]
    #pragma unroll
    for (int r = 0; r < 8; ++r) {
        const int row = ty * 8 + r;
        Ms[row * 16 + tx] = m[r];
        Is[row * 16 + tx] = mi[r];
    }
    __syncthreads();
    if (tid < BT) {
        float bm = Ms[tid * 16];
        int   bi = Is[tid * 16];
        #pragma unroll
        for (int k2 = 1; k2 < 16; ++k2) {
            const float mm = Ms[tid * 16 + k2];
            const int   ii = Is[tid * 16 + k2];
            if (mm < bm || (mm == bm && ii < bi)) { bm = mm; bi = ii; }
        }
        Idx[tid] = bi;
        // idx output (B,T) as float at tail of d_out
        out[(size_t)B_ * T_ * D_ + (size_t)(b0 + tid) * T_ + t] = (float)bi;
    }
    __syncthreads();

    // fused gather: embed[b][t][:] = codebook[t][idx][:]  (1 row per wave-iter)
    const int w = tid >> 6, lane = tid & 63;
    for (int i = 0; i < 32; ++i) {
        const int row = w * 32 + i;
        const int idx = Idx[row];
        const float4 src = *(const float4*)(cb + ((size_t)t * V_ + idx) * D_ + lane * 4);
        *(float4*)(out + (((size_t)(b0 + row)) * T_ + t) * D_ + lane * 4) = src;
    }
}

extern "C" void kernel_launch(void* const* d_in, const int* in_sizes, int n_in,
                              void* d_out, int out_size, void* d_ws, size_t ws_size,
                              hipStream_t stream) {
    const float* x  = (const float*)d_in[0];   // (B,T,D)
    const float* cb = (const float*)d_in[1];   // (T,V,D)
    float* out = (float*)d_out;                // embed (B,T,D) fp32 ++ idx (B,T) as float
    float* c2  = (float*)d_ws;                 // T*V floats = 128 KB

    c2_kernel<<<dim3(T_ * V_ / 4), 256, 0, stream>>>(cb, c2);
    vq_kernel<<<dim3(T_, B_ / BT), 256, 0, stream>>>(x, cb, c2, out);
}

// Round 2
// 285.768 us; speedup vs baseline: 1.9750x; 1.9750x over previous
//
#include <hip/hip_runtime.h>
#include <hip/hip_bf16.h>

// B=2048, T=32, V=1024, D=256
// embed[b][t][:] = codebook[t][argmin_v (c2[v] - 2*x.c)], idx likewise.
// Strategy: bf16 MFMA screen (2 sweeps: min, then margin-candidates) + exact
// fp32 rescore of ~1.5 candidates/row. Margin 8.0 deterministically covers the
// worst-case bf16 rounding error (2 * 2^-8 * ||x|| * ||c|| <= ~3 per score).

#define B_ 2048
#define T_ 32
#define V_ 1024
#define D_ 256

#define BT 128        // rows per block
#define VT 128        // v per tile
#define NVT (V_ / VT) // 8
#define CAND_MAX 512
#define MARGIN 8.0f

typedef __attribute__((ext_vector_type(8))) short short8;   // 8 bf16 = 4 VGPR
typedef __attribute__((ext_vector_type(4))) float f32x4;    // mfma acc

// ---- bf16 round-to-nearest-even (finite inputs only) ----
__device__ __forceinline__ unsigned short f2bf(float f) {
    unsigned u = __builtin_bit_cast(unsigned, f);
    unsigned r = u + 0x7FFFu + ((u >> 16) & 1u);
    return (unsigned short)(r >> 16);
}

__device__ __forceinline__ short8 pack8(float4 a, float4 b) {
    short8 r;
    r[0] = (short)f2bf(a.x); r[1] = (short)f2bf(a.y);
    r[2] = (short)f2bf(a.z); r[3] = (short)f2bf(a.w);
    r[4] = (short)f2bf(b.x); r[5] = (short)f2bf(b.y);
    r[6] = (short)f2bf(b.z); r[7] = (short)f2bf(b.w);
    return r;
}

// ---------------- prep: c2[t*V+v] = sum_d codebook^2 (exact fp32) ----------
__global__ void c2_kernel(const float* __restrict__ cb, float* __restrict__ c2) {
    int row  = blockIdx.x * 4 + (threadIdx.x >> 6);
    int lane = threadIdx.x & 63;
    const float4 v = ((const float4*)(cb + (size_t)row * D_))[lane];
    float s = v.x * v.x + v.y * v.y + v.z * v.z + v.w * v.w;
    #pragma unroll
    for (int off = 32; off > 0; off >>= 1) s += __shfl_down(s, off, 64);
    if (lane == 0) c2[row] = s;
}

// ---------------- main ----------------
__global__ __launch_bounds__(256, 2)
void vq_kernel(const float* __restrict__ x, const float* __restrict__ cb,
               const float* __restrict__ c2, float* __restrict__ out) {
    const int t  = blockIdx.x;
    const int b0 = blockIdx.y * BT;

    // LDS: 65536 + 10240 + 1024 + 512 + 1024 + 2048 + 4 + 512 = 80,900 B
    __shared__ short8 A_lds[4096];              // 128 rows x 32 granules, swizzled
    __shared__ short8 Bc_lds[640];              // 128 rows x 5 granules (4 data + 1 pad)
    __shared__ float  minPart[BT * 2];
    __shared__ float  minS[BT];
    __shared__ unsigned long long result[BT];
    __shared__ unsigned s_cand[CAND_MAX];
    __shared__ unsigned s_cnt;
    __shared__ int    IdxS[BT];

    const int tid  = threadIdx.x;
    const int wave = tid >> 6, lane = tid & 63;
    const int wm = wave & 1, wn = wave >> 1;    // 2x2 wave grid, wave tile 64x64
    const int q  = lane >> 4, ln = lane & 15;

    if (tid < BT) result[tid] = ~0ULL;
    if (tid == 0) s_cnt = 0;

    // ---- stage A once: x rows -> bf16, XOR-swizzled (2-way conflicts = free)
    #pragma unroll
    for (int i = 0; i < 16; ++i) {
        int gid = i * 256 + tid;
        int r = gid >> 5, g = gid & 31;
        const float4* src = (const float4*)(x + (((size_t)(b0 + r)) * T_ + t) * D_ + g * 8);
        A_lds[r * 32 + (g ^ (r & 15))] = pack8(src[0], src[1]);
    }

    // ---- one K=32 chunk of B staged per step (stride 40 bf16: 2-way = free)
    auto stage_B = [&](int vt, int kc) {
        #pragma unroll
        for (int i = 0; i < 2; ++i) {
            int gid = i * 256 + tid;
            int r = gid >> 2, g = gid & 3;
            const float4* src = (const float4*)(cb + ((size_t)t * V_ + vt * VT + r) * D_ + kc * 32 + g * 8);
            Bc_lds[r * 5 + g] = pack8(src[0], src[1]);
        }
    };

    auto mfma_vt = [&](int vt, f32x4 (&acc)[4][4]) {
        #pragma unroll
        for (int mt = 0; mt < 4; ++mt)
            #pragma unroll
            for (int nt = 0; nt < 4; ++nt) acc[mt][nt] = (f32x4){0.f, 0.f, 0.f, 0.f};
        for (int kc = 0; kc < 8; ++kc) {
            __syncthreads();               // previous chunk's readers done
            stage_B(vt, kc);
            __syncthreads();
            short8 af[4], bf[4];
            #pragma unroll
            for (int mt = 0; mt < 4; ++mt) {
                int m = wm * 64 + mt * 16 + ln;
                af[mt] = A_lds[m * 32 + ((kc * 4 + q) ^ ln)];
            }
            #pragma unroll
            for (int nt = 0; nt < 4; ++nt) {
                int n = wn * 64 + nt * 16 + ln;
                bf[nt] = Bc_lds[n * 5 + q];
            }
            #pragma unroll
            for (int mt = 0; mt < 4; ++mt)
                #pragma unroll
                for (int nt = 0; nt < 4; ++nt)
                    acc[mt][nt] = __builtin_amdgcn_mfma_f32_16x16x32_bf16(af[mt], bf[nt], acc[mt][nt], 0, 0, 0);
        }
    };

    // ================= sweep 1: per-row approx min (value only) ============
    float runmin[16];
    #pragma unroll
    for (int s = 0; s < 16; ++s) runmin[s] = 3.4e38f;

    for (int vt = 0; vt < NVT; ++vt) {
        f32x4 acc[4][4];
        mfma_vt(vt, acc);
        const float* c2p = c2 + t * V_ + vt * VT + wn * 64 + ln;
        #pragma unroll
        for (int nt = 0; nt < 4; ++nt) {
            const float cc = c2p[nt * 16];
            #pragma unroll
            for (int mt = 0; mt < 4; ++mt)
                #pragma unroll
                for (int i = 0; i < 4; ++i) {
                    float s = fmaf(-2.0f, acc[mt][nt][i], cc);
                    runmin[mt * 4 + i] = fminf(runmin[mt * 4 + i], s);
                }
        }
    }

    // reduce min across the 16 n-lanes, then across the 2 n-waves
    #pragma unroll
    for (int s = 0; s < 16; ++s) {
        float v = runmin[s];
        v = fminf(v, __shfl_xor(v, 1, 64));
        v = fminf(v, __shfl_xor(v, 2, 64));
        v = fminf(v, __shfl_xor(v, 4, 64));
        v = fminf(v, __shfl_xor(v, 8, 64));
        runmin[s] = v;
    }
    if (ln == 0) {
        #pragma unroll
        for (int s = 0; s < 16; ++s) {
            int row = wm * 64 + (s >> 2) * 16 + q * 4 + (s & 3);
            minPart[row * 2 + wn] = runmin[s];
        }
    }
    __syncthreads();
    if (tid < BT) minS[tid] = fminf(minPart[tid * 2], minPart[tid * 2 + 1]) + MARGIN;
    __syncthreads();
    float thr[16];
    #pragma unroll
    for (int s = 0; s < 16; ++s)
        thr[s] = minS[wm * 64 + (s >> 2) * 16 + q * 4 + (s & 3)];

    // ================= sweep 2: identical recompute, collect candidates ====
    for (int vt = 0; vt < NVT; ++vt) {
        f32x4 acc[4][4];
        mfma_vt(vt, acc);
        const float* c2p = c2 + t * V_ + vt * VT + wn * 64 + ln;
        #pragma unroll
        for (int nt = 0; nt < 4; ++nt) {
            const float cc = c2p[nt * 16];
            const int v = vt * VT + wn * 64 + nt * 16 + ln;
            #pragma unroll
            for (int mt = 0; mt < 4; ++mt)
                #pragma unroll
                for (int i = 0; i < 4; ++i) {
                    float s = fmaf(-2.0f, acc[mt][nt][i], cc);
                    if (s < thr[mt * 4 + i]) {
                        int row = wm * 64 + mt * 16 + q * 4 + i;
                        unsigned pos = atomicAdd(&s_cnt, 1u);
                        if (pos < CAND_MAX) s_cand[pos] = (unsigned)((row << 10) | v);
                    }
                }
        }
    }

    // ================= exact fp32 rescore of candidates ====================
    __syncthreads();
    const unsigned ncand = min(s_cnt, (unsigned)CAND_MAX);
    const int grp = tid >> 4, l16 = tid & 15;
    for (unsigned ci = grp; ci < ncand; ci += 16) {
        const unsigned e = s_cand[ci];
        const int row = e >> 10, v = e & 1023;
        const float* xr = x + (((size_t)(b0 + row)) * T_ + t) * D_ + l16 * 16;
        const float* cr = cb + ((size_t)t * V_ + v) * D_ + l16 * 16;
        float dot = 0.f;
        #pragma unroll
        for (int j = 0; j < 4; ++j) {
            float4 a = *(const float4*)(xr + j * 4);
            float4 b = *(const float4*)(cr + j * 4);
            dot = fmaf(a.x, b.x, dot); dot = fmaf(a.y, b.y, dot);
            dot = fmaf(a.z, b.z, dot); dot = fmaf(a.w, b.w, dot);
        }
        dot += __shfl_xor(dot, 1, 64);
        dot += __shfl_xor(dot, 2, 64);
        dot += __shfl_xor(dot, 4, 64);
        dot += __shfl_xor(dot, 8, 64);
        if (l16 == 0) {
            float sc = fmaf(-2.0f, dot, c2[t * V_ + v]);
            unsigned u = __builtin_bit_cast(unsigned, sc);
            u = (u & 0x80000000u) ? ~u : (u | 0x80000000u);   // sortable fp32
            unsigned long long pk = ((unsigned long long)u << 32) | (unsigned)v;
            atomicMin(&result[row], pk);
        }
    }
    __syncthreads();

    if (tid < BT) {
        const int idx = (int)(result[tid] & 0xFFFFFFFFull);
        IdxS[tid] = idx;
        out[(size_t)B_ * T_ * D_ + (size_t)(b0 + tid) * T_ + t] = (float)idx;
    }
    __syncthreads();

    // ================= fused gather ========================================
    const int w = tid >> 6, gl = tid & 63;
    #pragma unroll
    for (int i = 0; i < 32; ++i) {
        const int row = w * 32 + i;
        const int idx = IdxS[row];
        const float4 src = *(const float4*)(cb + ((size_t)t * V_ + idx) * D_ + gl * 4);
        *(float4*)(out + (((size_t)(b0 + row)) * T_ + t) * D_ + gl * 4) = src;
    }
}

extern "C" void kernel_launch(void* const* d_in, const int* in_sizes, int n_in,
                              void* d_out, int out_size, void* d_ws, size_t ws_size,
                              hipStream_t stream) {
    const float* x  = (const float*)d_in[0];   // (B,T,D)
    const float* cb = (const float*)d_in[1];   // (T,V,D)
    float* out = (float*)d_out;                // embed fp32 ++ idx (as float)
    float* c2  = (float*)d_ws;                 // 32*1024*4 = 128 KB

    c2_kernel<<<dim3(T_ * V_ / 4), 256, 0, stream>>>(cb, c2);
    vq_kernel<<<dim3(T_, B_ / BT), 256, 0, stream>>>(x, cb, c2, out);
}

// Round 3
// 281.945 us; speedup vs baseline: 2.0018x; 1.0136x over previous
//
#include <hip/hip_runtime.h>
#include <hip/hip_bf16.h>

// B=2048, T=32, V=1024, D=256
// idx[b][t] = argmin_v (c2[t][v] - 2*x[b][t].c[t][v]);  embed = gathered codebook rows.
// Single bf16-MFMA sweep with running-threshold candidate collection (superset
// of {v: score < final_min + MARGIN}), exact fp32 rescore of ~600 candidates,
// fused gather. Codebook pre-converted to bf16 and pre-swizzled into LDS order
// so B-staging is pure global_load_lds (no VALU), when ws_size permits.

#define B_ 2048
#define T_ 32
#define V_ 1024
#define D_ 256
#define BT 128
#define VT 128
#define NVT 8
#define CAND_MAX 1280
#define MARGIN 8.0f

typedef __attribute__((ext_vector_type(8))) short short8;   // 8 bf16 = 4 VGPR
typedef __attribute__((ext_vector_type(4))) float f32x4;

__device__ __forceinline__ unsigned short f2bf(float f) {
    unsigned u = __builtin_bit_cast(unsigned, f);
    unsigned r = u + 0x7FFFu + ((u >> 16) & 1u);
    return (unsigned short)(r >> 16);
}

__device__ __forceinline__ short8 pack8(float4 a, float4 b) {
    short8 r;
    r[0] = (short)f2bf(a.x); r[1] = (short)f2bf(a.y);
    r[2] = (short)f2bf(a.z); r[3] = (short)f2bf(a.w);
    r[4] = (short)f2bf(b.x); r[5] = (short)f2bf(b.y);
    r[6] = (short)f2bf(b.z); r[7] = (short)f2bf(b.w);
    return r;
}

__device__ __forceinline__ void load_lds16(const void* g, void* l) {
    __builtin_amdgcn_global_load_lds(
        (const __attribute__((address_space(1))) unsigned int*)g,
        (__attribute__((address_space(3))) unsigned int*)l, 16, 0, 0);
}

// ---- prep (fused): c2 exact fp32 + codebook -> bf16 pre-swizzled LDS layout
// cbs tile (t,vt,kc) = 8192 B: slot (r,gs) 16B holds logical granule gs^(r&3).
__global__ void prep_kernel(const float* __restrict__ cb, float* __restrict__ c2,
                            unsigned short* __restrict__ cbs) {
    const int wave = threadIdx.x >> 6, lane = threadIdx.x & 63;
    const int row = blockIdx.x * 4 + wave;                 // t*V + v
    const float4 v4 = *(const float4*)(cb + (size_t)row * D_ + lane * 4);
    float s = v4.x * v4.x + v4.y * v4.y + v4.z * v4.z + v4.w * v4.w;
    #pragma unroll
    for (int off = 32; off; off >>= 1) s += __shfl_down(s, off, 64);
    if (lane == 0) c2[row] = s;

    ushort4 b4;
    b4.x = f2bf(v4.x); b4.y = f2bf(v4.y); b4.z = f2bf(v4.z); b4.w = f2bf(v4.w);
    const int t = row >> 10, v = row & 1023, vt = v >> 7, r7 = v & 127;
    const int kc = lane >> 3, g = (lane >> 1) & 3, half = lane & 1;
    const size_t off_us = ((size_t)((t * NVT + vt) * 8 + kc)) * 4096
                        + (size_t)(r7 * 4 + (g ^ (r7 & 3))) * 8 + half * 4;
    *(ushort4*)(cbs + off_us) = b4;
}

// ---- fallback prep when ws too small: c2 only
__global__ void c2_kernel(const float* __restrict__ cb, float* __restrict__ c2) {
    const int row = blockIdx.x * 4 + (threadIdx.x >> 6);
    const int lane = threadIdx.x & 63;
    const float4 v = ((const float4*)(cb + (size_t)row * D_))[lane];
    float s = v.x * v.x + v.y * v.y + v.z * v.z + v.w * v.w;
    #pragma unroll
    for (int off = 32; off; off >>= 1) s += __shfl_down(s, off, 64);
    if (lane == 0) c2[row] = s;
}

// ---------------- main ----------------
__global__ __launch_bounds__(256, 2)
void vq_kernel(const float* __restrict__ x, const float* __restrict__ cb,
               const float* __restrict__ c2, const unsigned short* __restrict__ cbs,
               float* __restrict__ out, int use_swz) {
    const int t  = blockIdx.x;
    const int b0 = blockIdx.y * BT;

    // LDS = 65536 + 8192 + 1024 + 1024 + 5120 + 4 = 80,900 B  -> 2 blocks/CU
    __shared__ short8 A_lds[4096];            // 128 rows x 32 granules, XOR(r&15)
    __shared__ short8 B_lds[512];             // 128 rows x 4 granules, XOR(r&3)
    __shared__ float  minPart[BT * 2];        // cumulative row-min per wn half
    __shared__ unsigned long long result[BT];
    __shared__ unsigned s_cand[CAND_MAX];
    __shared__ unsigned s_cnt;

    const int tid = threadIdx.x;
    const int wave = tid >> 6, lane = tid & 63;
    const int wm = wave & 1, wn = wave >> 1;
    const int q = lane >> 4, ln = lane & 15;

    if (tid < BT) result[tid] = ~0ULL;
    minPart[tid] = 3.4e38f;
    if (tid == 0) s_cnt = 0;

    // stage A once (fp32 -> bf16, XOR swizzle; once per block so VALU cost ok)
    #pragma unroll
    for (int i = 0; i < 16; ++i) {
        int gid = i * 256 + tid, r = gid >> 5, g = gid & 31;
        const float4* src = (const float4*)(x + (((size_t)(b0 + r)) * T_ + t) * D_ + g * 8);
        A_lds[r * 32 + (g ^ (r & 15))] = pack8(src[0], src[1]);
    }

    auto stage_B = [&](int vt, int kc) {
        if (use_swz) {
            const unsigned short* tile = cbs + ((size_t)((t * NVT + vt) * 8 + kc)) * 4096;
            #pragma unroll
            for (int i = 0; i < 2; ++i) {
                const int gr = wave * 128 + i * 64;   // granule base (wave-uniform)
                load_lds16(tile + (size_t)(gr + lane) * 8, (void*)(B_lds + gr));
            }
        } else {
            #pragma unroll
            for (int i = 0; i < 2; ++i) {
                int gid = i * 256 + tid, r = gid >> 2, g = gid & 3;
                const float4* src = (const float4*)(cb + ((size_t)t * V_ + vt * VT + r) * D_ + kc * 32 + g * 8);
                B_lds[r * 4 + (g ^ (r & 3))] = pack8(src[0], src[1]);
            }
        }
    };

    stage_B(0, 0);
    __syncthreads();   // A writes + B chunk0 landed (lgkmcnt + vmcnt drained)

    for (int vt = 0; vt < NVT; ++vt) {
        f32x4 acc[4][4];
        #pragma unroll
        for (int mt = 0; mt < 4; ++mt)
            #pragma unroll
            for (int nt = 0; nt < 4; ++nt) acc[mt][nt] = (f32x4){0.f, 0.f, 0.f, 0.f};

        for (int kc = 0; kc < 8; ++kc) {
            short8 af[4], bfr[4];
            #pragma unroll
            for (int mt = 0; mt < 4; ++mt) {
                int m = wm * 64 + mt * 16 + ln;
                af[mt] = A_lds[m * 32 + ((kc * 4 + q) ^ ln)];
            }
            #pragma unroll
            for (int nt = 0; nt < 4; ++nt) {
                int n = wn * 64 + nt * 16 + ln;
                bfr[nt] = B_lds[n * 4 + (q ^ (n & 3))];
            }
            __syncthreads();                 // frags in regs; B_lds reusable
            if (!(vt == NVT - 1 && kc == 7)) {
                int nk = kc + 1, nv = vt;
                if (nk == 8) { nk = 0; nv = vt + 1; }
                stage_B(nv, nk);             // overlaps with MFMA below
            }
            #pragma unroll
            for (int mt = 0; mt < 4; ++mt)
                #pragma unroll
                for (int nt = 0; nt < 4; ++nt)
                    acc[mt][nt] = __builtin_amdgcn_mfma_f32_16x16x32_bf16(af[mt], bfr[nt], acc[mt][nt], 0, 0, 0);
            __syncthreads();                 // staging landed
        }

        // ---- epilogue: update shared running row-min, then collect candidates
        const float* c2p = c2 + t * V_ + vt * VT + wn * 64 + ln;
        float cc[4];
        #pragma unroll
        for (int nt = 0; nt < 4; ++nt) cc[nt] = c2p[nt * 16];

        #pragma unroll
        for (int mt = 0; mt < 4; ++mt)
            #pragma unroll
            for (int i = 0; i < 4; ++i) {
                float mn = 3.4e38f;
                #pragma unroll
                for (int nt = 0; nt < 4; ++nt)
                    mn = fminf(mn, fmaf(-2.0f, acc[mt][nt][i], cc[nt]));
                mn = fminf(mn, __shfl_xor(mn, 1, 64));
                mn = fminf(mn, __shfl_xor(mn, 2, 64));
                mn = fminf(mn, __shfl_xor(mn, 4, 64));
                mn = fminf(mn, __shfl_xor(mn, 8, 64));
                if (ln == 0) {
                    int r = wm * 64 + mt * 16 + q * 4 + i;
                    minPart[r * 2 + wn] = fminf(minPart[r * 2 + wn], mn);
                }
            }
        __syncthreads();

        #pragma unroll
        for (int mt = 0; mt < 4; ++mt)
            #pragma unroll
            for (int i = 0; i < 4; ++i) {
                int r = wm * 64 + mt * 16 + q * 4 + i;
                float2 mp = *(const float2*)&minPart[r * 2];
                float thr = fminf(mp.x, mp.y) + MARGIN;
                #pragma unroll
                for (int nt = 0; nt < 4; ++nt) {
                    float s = fmaf(-2.0f, acc[mt][nt][i], cc[nt]);
                    if (s < thr) {
                        int v = vt * VT + wn * 64 + nt * 16 + ln;
                        unsigned pos = atomicAdd(&s_cnt, 1u);
                        if (pos < CAND_MAX) s_cand[pos] = (unsigned)((r << 10) | v);
                    }
                }
            }
        // no barrier needed: next tile's frag reads don't conflict with these ops
    }

    // ---- exact fp32 rescore of candidates (16-lane groups)
    __syncthreads();
    const unsigned ncand = min(s_cnt, (unsigned)CAND_MAX);
    const int grp = tid >> 4, l16 = tid & 15;
    for (unsigned ci = grp; ci < ncand; ci += 16) {
        const unsigned e = s_cand[ci];
        const int row = e >> 10, v = e & 1023;
        const float* xr = x + (((size_t)(b0 + row)) * T_ + t) * D_ + l16 * 16;
        const float* cr = cb + ((size_t)t * V_ + v) * D_ + l16 * 16;
        float dot = 0.f;
        #pragma unroll
        for (int j = 0; j < 4; ++j) {
            float4 a = *(const float4*)(xr + j * 4);
            float4 b = *(const float4*)(cr + j * 4);
            dot = fmaf(a.x, b.x, dot); dot = fmaf(a.y, b.y, dot);
            dot = fmaf(a.z, b.z, dot); dot = fmaf(a.w, b.w, dot);
        }
        dot += __shfl_xor(dot, 1, 64);
        dot += __shfl_xor(dot, 2, 64);
        dot += __shfl_xor(dot, 4, 64);
        dot += __shfl_xor(dot, 8, 64);
        if (l16 == 0) {
            float sc = fmaf(-2.0f, dot, c2[t * V_ + v]);
            unsigned u = __builtin_bit_cast(unsigned, sc);
            u = (u & 0x80000000u) ? ~u : (u | 0x80000000u);   // sortable fp32
            atomicMin(&result[row], ((unsigned long long)u << 32) | (unsigned)v);
        }
    }
    __syncthreads();

    if (tid < BT)
        out[(size_t)B_ * T_ * D_ + (size_t)(b0 + tid) * T_ + t] =
            (float)(int)(result[tid] & 1023u);

    // ---- fused gather
    const int w = tid >> 6, gl = tid & 63;
    #pragma unroll
    for (int i = 0; i < 32; ++i) {
        const int row = w * 32 + i;
        const int idx = (int)(result[row] & 1023u);
        const float4 src = *(const float4*)(cb + ((size_t)t * V_ + idx) * D_ + gl * 4);
        *(float4*)(out + (((size_t)(b0 + row)) * T_ + t) * D_ + gl * 4) = src;
    }
}

extern "C" void kernel_launch(void* const* d_in, const int* in_sizes, int n_in,
                              void* d_out, int out_size, void* d_ws, size_t ws_size,
                              hipStream_t stream) {
    const float* x  = (const float*)d_in[0];   // (B,T,D)
    const float* cb = (const float*)d_in[1];   // (T,V,D)
    float* out = (float*)d_out;                // embed fp32 ++ idx (as float)
    float* c2  = (float*)d_ws;                 // 32768 floats = 128 KB
    unsigned short* cbs = (unsigned short*)((char*)d_ws + 131072);  // 16 MB
    const size_t NEED = 131072 + (size_t)T_ * V_ * D_ * 2;
    const int use_swz = (ws_size >= NEED) ? 1 : 0;

    if (use_swz) prep_kernel<<<dim3(T_ * V_ / 4), 256, 0, stream>>>(cb, c2, cbs);
    else         c2_kernel<<<dim3(T_ * V_ / 4), 256, 0, stream>>>(cb, c2);
    vq_kernel<<<dim3(T_, B_ / BT), 256, 0, stream>>>(x, cb, c2, cbs, out, use_swz);
}